// Round 2
// baseline (4835.919 us; speedup 1.0000x reference)
//
#include <hip/hip_runtime.h>
#include <stdint.h>

// Word2MatEncoder: out[b] = prod_{s=0..63} table[sent[b,s]]  (28x28 fp32 chain)
//
// R7 (= R6 with the declaration-order compile fix): R5 was latency-bound
// (VALUBusy 31%, Occupancy 9%): single-buffered LDS + __syncthreads forced a
// vmcnt(0)/lgkmcnt(0) drain every step, exposing the full 28KB-per-step DMA
// drain (~1-3k cyc) against a 6.3k-cyc matmul, with ~0.9 waves/SIMD so
// nothing hides it. Also the unrolled body (~56KB) blew the 32KB I-cache.
// Redesign: 2 tasks/wave x 28 lanes x 1 row/lane.
//  - LDS per buffer = 2 matrices = 6.3KB -> true double-buffer at 14.3KB
//    -> ~11 resident blocks/CU (~2.75 waves/SIMD): TLP is back.
//  - Single-wave blocks: NO __syncthreads anywhere. Coherence via explicit
//    s_waitcnt only. Main loop waits vmcnt(7): the next matrix's 7 chunks
//    stay in flight across the matmul (counted-vmcnt pipelining, m218-style).
//    Peeled final step waits vmcnt(0).
//  - DMA layout: the 2 task matrices are one linear 6272B stream in LDS.
//    Chunk c (64 lanes x 16B) covers float4 indices [64c,64c+64); per-lane
//    source = p0/p1 selected by position (lane-divergence-free cndmask).
//    Chunk 6 has 8 valid lanes (exec-masked); LDS dest = uniform base (HW
//    adds lane*16). Matrix m is contiguous row-major at float offset m*784:
//    task reads are 28-lane broadcasts; task bases 3136B apart -> bank+16,
//    conflict-free.
//  - Body ~2.1k insts (~17KB): fits I-cache.
// Same (16,4) segmentation and identical k-ascending fmaf chains as R5 ->
// bit-identical numerics. fp32 throughout (no fp32 MFMA on CDNA4).

#define D 28
#define EMB 784
#define SEQ 64
#define NITEMS 2048
#define TPW 2            // tasks per wave
#define LPT 28           // lanes per task (1 row each)
#define NCH 7            // DMA chunks per 2-matrix stage (6272B -> 7KB padded)
#define CHF 256          // floats per chunk (64 lanes x 16B)
#define BUF_F (NCH * CHF)  // 1792 floats = 7168 B per buffer

typedef __attribute__((address_space(3))) uint32_t lds_u32;
typedef const __attribute__((address_space(1))) uint32_t glb_u32;

// Stage both task matrices (p0, p1) for one step into buf (linear stream).
__device__ __forceinline__ void dma_pair(const float* p0, const float* p1,
                                         float* buf, int lane) {
#pragma unroll
  for (int c = 0; c < NCH; ++c) {
    const int fq = c * 64 + lane;  // float4 index in [0,448); valid < 392
    const float* src = (fq < 196)   ? (p0 + 4 * fq)
                       : (fq < 392) ? (p1 + 4 * (fq - 196))
                                    : p1;  // never issued (masked below)
    if (c < NCH - 1 || lane < 8)
      __builtin_amdgcn_global_load_lds((glb_u32*)src, (lds_u32*)(buf + c * CHF),
                                       16, 0, 0);
  }
}

// Cc(row rl of task tloc) = Aa @ M, M staged row-major at lds[cur]+tloc*EMB.
#define MATMUL(Aa, Cc)                                                         \
  do {                                                                         \
    const float* Bp = &lds[cur][0] + tloc * EMB;                               \
    _Pragma("unroll") for (int k = 0; k < D; ++k) {                            \
      const float a = Aa[k];                                                   \
      _Pragma("unroll") for (int jv = 0; jv < 7; ++jv) {                       \
        float4 m = *(const float4*)(Bp + k * D + 4 * jv);                      \
        if (k == 0) {                                                          \
          Cc[4 * jv + 0] = a * m.x;                                            \
          Cc[4 * jv + 1] = a * m.y;                                            \
          Cc[4 * jv + 2] = a * m.z;                                            \
          Cc[4 * jv + 3] = a * m.w;                                            \
        } else {                                                               \
          Cc[4 * jv + 0] = fmaf(a, m.x, Cc[4 * jv + 0]);                       \
          Cc[4 * jv + 1] = fmaf(a, m.y, Cc[4 * jv + 1]);                       \
          Cc[4 * jv + 2] = fmaf(a, m.z, Cc[4 * jv + 2]);                       \
          Cc[4 * jv + 3] = fmaf(a, m.w, Cc[4 * jv + 3]);                       \
        }                                                                      \
      }                                                                        \
    }                                                                          \
  } while (0)

// In-loop step: mat s is landed once <=7 loads outstanding (mat s+1 stays in
// flight). After compute, restage this buffer with mat s+2 and prefetch the
// s+3 pointers (hides the sent[] s_load latency one step ahead).
#define STEP(Aa, Cc)                                                           \
  do {                                                                         \
    asm volatile("s_waitcnt vmcnt(7)" ::: "memory");                           \
    __builtin_amdgcn_sched_barrier(0);                                         \
    MATMUL(Aa, Cc);                                                            \
    asm volatile("s_waitcnt lgkmcnt(0)" ::: "memory"); /* reads retired */     \
    __builtin_amdgcn_sched_barrier(0);                                         \
    if (s + 2 < SEG_LEN) dma_pair(np0, np1, &lds[cur][0], lane);               \
    {                                                                          \
      const int nn = (s + 3 < SEG_LEN) ? s + 3 : SEG_LEN - 1;                  \
      np0 = gmat(0, nn);                                                       \
      np1 = gmat(1, nn);                                                       \
    }                                                                          \
    cur ^= 1;                                                                  \
    ++s;                                                                       \
  } while (0)

#define STEP_LAST(Aa, Cc)                                                      \
  do {                                                                         \
    asm volatile("s_waitcnt vmcnt(0)" ::: "memory");                           \
    __builtin_amdgcn_sched_barrier(0);                                         \
    MATMUL(Aa, Cc);                                                            \
  } while (0)

// Product of SEG_LEN consecutive matrices (SEG_LEN-1 odd -> result in A1).
// GATHER: matrices are table[sp[s]]; else dense at src + (task*SEG_LEN+s)*EMB.
template <int SEG_LEN, int PSEG, bool GATHER>
__global__ __launch_bounds__(64, 2) void chain_kernel(
    const float* __restrict__ src, const int* __restrict__ sent,
    float* __restrict__ dst, int ntask) {
  __shared__ __align__(16) float lds[2][BUF_F];

  const int lane = threadIdx.x;
  int tloc = lane / LPT;
  int rl = lane - tloc * LPT;
  if (tloc >= TPW) { tloc = TPW - 1; rl = LPT - 1; }  // lanes 56-63 mirror
  const bool active = lane < TPW * LPT;

  int task0 = blockIdx.x * TPW;
  int task1 = task0 + 1;
  if (task0 >= ntask) task0 = ntask - 1;
  if (task1 >= ntask) task1 = ntask - 1;

  const int* sp0 = nullptr;
  const int* sp1 = nullptr;
  if (GATHER) {
    const int i0 = task0 / PSEG, g0 = task0 - i0 * PSEG;
    sp0 = sent + i0 * SEQ + g0 * SEG_LEN;
    const int i1 = task1 / PSEG, g1 = task1 - i1 * PSEG;
    sp1 = sent + i1 * SEQ + g1 * SEG_LEN;
  }

  auto gmat = [&](int t, int s_) -> const float* {
    if (GATHER) {
      const int* sp = t ? sp1 : sp0;
      return src + (size_t)sp[s_] * EMB;
    }
    const int tk = t ? task1 : task0;
    return src + ((size_t)tk * SEG_LEN + s_) * EMB;
  };

  float A0[D], A1[D];

  // A0 = this lane's row (rl) of its task's first matrix (direct loads,
  // issued before the DMAs so the prologue wait order stays pipelined).
  {
    const float* m0 = gmat(tloc, 0) + rl * D;
#pragma unroll
    for (int jv = 0; jv < 7; ++jv) {
      float4 v = *(const float4*)(m0 + 4 * jv);
      A0[4 * jv + 0] = v.x;
      A0[4 * jv + 1] = v.y;
      A0[4 * jv + 2] = v.z;
      A0[4 * jv + 3] = v.w;
    }
  }

  // stage mats 1 and 2 (14 chunks in flight); prefetch pointers for mat 3
  dma_pair(gmat(0, 1), gmat(1, 1), &lds[0][0], lane);
  {
    const int s2 = SEG_LEN > 2 ? 2 : 1;
    dma_pair(gmat(0, s2), gmat(1, s2), &lds[1][0], lane);
  }
  const float* np0 = gmat(0, SEG_LEN > 3 ? 3 : SEG_LEN - 1);
  const float* np1 = gmat(1, SEG_LEN > 3 ? 3 : SEG_LEN - 1);

  int s = 1, cur = 0;
#pragma unroll 1
  for (int p = 0; p < (SEG_LEN - 2) / 2; ++p) {
    STEP(A0, A1);
    STEP(A1, A0);
  }
  STEP_LAST(A0, A1);  // step SEG_LEN-1 -> result in A1

  if (active) {
    const int mytask = tloc ? task1 : task0;
    float* op = dst + (size_t)mytask * EMB + rl * D;
#pragma unroll
    for (int jv = 0; jv < 7; ++jv)
      *(float4*)(op + 4 * jv) =
          make_float4(A1[4 * jv + 0], A1[4 * jv + 1], A1[4 * jv + 2],
                      A1[4 * jv + 3]);
  }
}

extern "C" void kernel_launch(void* const* d_in, const int* in_sizes, int n_in,
                              void* d_out, int out_size, void* d_ws,
                              size_t ws_size, hipStream_t stream) {
  const float* table = (const float*)d_in[0];
  const int* sent = (const int*)d_in[1];
  float* out = (float*)d_out;

  const size_t need = (size_t)NITEMS * 4 * EMB * sizeof(float);  // 25.7 MB
  if (ws_size >= need) {
    float* pbuf = (float*)d_ws;
    // phase 1: 4 segments of 16 per item -> 8192 partials
    const int nt1 = NITEMS * 4;
    chain_kernel<16, 4, true><<<nt1 / TPW, 64, 0, stream>>>(table, sent, pbuf,
                                                            nt1);
    // phase 2: chain each item's 4 partials -> d_out
    chain_kernel<4, 1, false><<<NITEMS / TPW, 64, 0, stream>>>(pbuf, nullptr,
                                                               out, NITEMS);
  } else {
    // fallback: direct 64-long chain per item straight into d_out
    chain_kernel<64, 1, true><<<NITEMS / TPW, 64, 0, stream>>>(table, sent, out,
                                                               NITEMS);
  }
}

// Round 3
// 419.382 us; speedup vs baseline: 11.5311x; 11.5311x over previous
//
#include <hip/hip_runtime.h>
#include <stdint.h>

// Word2MatEncoder: out[b] = prod_{s=0..63} table[sent[b,s]]  (28x28 fp32 chain)
//
// R8: R7's redesign exploded HBM traffic (WRITE 25MB -> 10GB, FETCH 198MB ->
// 5.2GB; VALUBusy 1.5%) -- compiler-generated per-thread memory round-trips in
// the new codegen (rule-#20-class), not a scheduling effect. Reverted phase 1
// to the verbatim R5 kernel (proven 262us total, sane counters).
// The recoverable win: R0 profile shows phase 2 (chain 4 partials/item) also
// costs ~124us despite a ~2us FLOP floor -- it ran the heavy chain_kernel at
// grid=228 (0.9 blocks/CU, serial DMA). New dedicated combine4 kernel:
//  - 2 items/wave x 28 lanes x 1 row/lane; grid 1024 -> fully resident.
//  - all 4 partial matrices -> registers upfront (independent loads, one
//    HBM round-trip), B broadcast via 12.5KB LDS with plain ds_write/ds_read
//    (single-wave blocks: no barriers; explicit lgkmcnt(0)+sched_barrier(0)
//    fences per guide rule #18; double-buffered to dodge FIFO questions).
//  - 3 fully-unrolled static-index matmuls (named ping-pong arrays).
// Phase 1 untouched. fp32 throughout (no fp32 MFMA on CDNA4; bf16 error
// compounds over 63 muls).

#define D 28
#define EMB 784
#define SEQ 64
#define NITEMS 2048
#define LPI 7            // lanes per task (phase 1)
#define IPW 9            // tasks per wave (phase 1)
#define RPL 4            // rows of the running product per lane (phase 1)
#define NCHUNK 28        // DMA chunks per matrix-set (1 row x 9 slots each)
#define CHUNK_F 256      // floats per chunk (64 lanes x 16B)
#define BUF_F (NCHUNK * CHUNK_F)  // 7168 floats = 28672 B

typedef __attribute__((address_space(3))) uint32_t lds_u32;
typedef const __attribute__((address_space(1))) uint32_t glb_u32;

// ---------------- phase 1: verbatim R5 chain kernel ----------------

// Stage one matrix per slot into LDS. glane = matrix base + rl*16B (per lane);
// chunk t pulls row t (bytes [t*112, t*112+16) per lane) of each slot's matrix.
__device__ __forceinline__ void dma_mat(const float* glane, float* lds0) {
#pragma unroll
  for (int t = 0; t < NCHUNK; ++t)
    __builtin_amdgcn_global_load_lds((glb_u32*)(glane + t * D),
                                     (lds_u32*)(lds0 + t * CHUNK_F), 16, 0, 0);
}

// Cc = Aa @ M   (M staged in LDS at Bs with the chunk layout above)
#define MATMUL(Aa, Cc)                                                         \
  do {                                                                         \
    _Pragma("unroll") for (int k = 0; k < D; ++k) {                            \
      _Pragma("unroll") for (int jv = 0; jv < 7; ++jv) {                       \
        float4 m = *(const float4*)(Bs + k * CHUNK_F + 4 * jv);                \
        _Pragma("unroll") for (int r = 0; r < RPL; ++r) {                      \
          float a = Aa[r][k];                                                  \
          if (k == 0) {                                                        \
            Cc[r][4 * jv + 0] = a * m.x;                                       \
            Cc[r][4 * jv + 1] = a * m.y;                                       \
            Cc[r][4 * jv + 2] = a * m.z;                                       \
            Cc[r][4 * jv + 3] = a * m.w;                                       \
          } else {                                                             \
            Cc[r][4 * jv + 0] = fmaf(a, m.x, Cc[r][4 * jv + 0]);               \
            Cc[r][4 * jv + 1] = fmaf(a, m.y, Cc[r][4 * jv + 1]);               \
            Cc[r][4 * jv + 2] = fmaf(a, m.z, Cc[r][4 * jv + 2]);               \
            Cc[r][4 * jv + 3] = fmaf(a, m.w, Cc[r][4 * jv + 3]);               \
          }                                                                    \
        }                                                                      \
      }                                                                        \
    }                                                                          \
  } while (0)

// One chain step: wait staged matrix, multiply, then DMA the next one.
#define STEP(Aa, Cc)                                                           \
  do {                                                                         \
    __builtin_amdgcn_s_waitcnt(0x0f70); /* vmcnt(0): matrix landed */          \
    __syncthreads();                                                           \
    MATMUL(Aa, Cc);                                                            \
    __syncthreads(); /* all LDS reads drained before overwrite */              \
    if (s + 1 < SEG_LEN) {                                                     \
      dma_mat(gn, lds);                                                        \
      int nn = (s + 2 < SEG_LEN) ? s + 2 : SEG_LEN - 1;                        \
      gn = glane(nn);                                                          \
    }                                                                          \
    ++s;                                                                       \
  } while (0)

// Product of SEG_LEN consecutive matrices (SEG_LEN-1 odd -> result in A1).
// GATHER: matrices are table[sp[s]]; else dense at src + (task*SEG_LEN+s)*EMB.
template <int SEG_LEN, int PSEG, bool GATHER>
__global__ __launch_bounds__(64, 1) void chain_kernel(
    const float* __restrict__ src, const int* __restrict__ sent,
    float* __restrict__ dst, int ntask) {
  __shared__ __align__(16) float lds[BUF_F];

  const int lane = threadIdx.x;
  int slot = lane / LPI;
  int rl = lane - slot * LPI;
  if (slot >= IPW) { slot = IPW - 1; rl = LPI - 1; }  // lane 63 mirrors lane 62
  int task = blockIdx.x * IPW + slot;
  if (task >= ntask) task = ntask - 1;  // tail duplicates (same values, benign)

  const int* sp = nullptr;
  if (GATHER) {
    const int item = task / PSEG;
    const int seg = task - item * PSEG;
    sp = sent + item * SEQ + seg * SEG_LEN;
  }
  auto glane = [&](int s) -> const float* {
    const float* m = GATHER ? src + (size_t)sp[s] * EMB
                            : src + ((size_t)task * SEG_LEN + s) * EMB;
    return m + rl * 4;  // this lane's 16B slice of each row
  };

  float A0[RPL][D], A1[RPL][D];

  // A0 = this lane's rows (rl*4 .. rl*4+3) of the first matrix (direct loads)
  {
    const float* m0 = GATHER ? src + (size_t)sp[0] * EMB
                             : src + (size_t)task * SEG_LEN * EMB;
#pragma unroll
    for (int r = 0; r < RPL; ++r) {
      const float* rp = m0 + (rl * RPL + r) * D;
#pragma unroll
      for (int jv = 0; jv < 7; ++jv) {
        float4 v = *(const float4*)(rp + 4 * jv);
        A0[r][4 * jv + 0] = v.x;
        A0[r][4 * jv + 1] = v.y;
        A0[r][4 * jv + 2] = v.z;
        A0[r][4 * jv + 3] = v.w;
      }
    }
  }

  // stage matrix 1; prefetch pointer for matrix 2
  dma_mat(glane(1), lds);
  const float* gn = glane(SEG_LEN > 2 ? 2 : 1);
  const float* Bs = lds + slot * (LPI * 4);  // slot*28 floats

  int s = 1;
#pragma unroll 1
  for (int p = 0; p < (SEG_LEN - 1) / 2; ++p) {
    STEP(A0, A1);
    STEP(A1, A0);
  }
  STEP(A0, A1);  // final step (SEG_LEN-1 is odd) -> result in A1

  // store
  {
    float* op = dst + (size_t)task * EMB;
#pragma unroll
    for (int r = 0; r < RPL; ++r) {
      float* rp = op + (rl * RPL + r) * D;
#pragma unroll
      for (int jv = 0; jv < 7; ++jv) {
        *(float4*)(rp + 4 * jv) =
            make_float4(A1[r][4 * jv + 0], A1[r][4 * jv + 1],
                        A1[r][4 * jv + 2], A1[r][4 * jv + 3]);
      }
    }
  }
}

// ---------------- phase 2: dedicated 4-partial combiner ----------------
// C(row rl) = Aa @ M with M row-major at LDS pointer Bp (28x28, contiguous).
// All indices compile-time (full unroll) -> registers, never scratch.
#define MATMUL2(Aa, Cc, Bp)                                                    \
  do {                                                                         \
    _Pragma("unroll") for (int k = 0; k < D; ++k) {                            \
      const float a = Aa[k];                                                   \
      _Pragma("unroll") for (int jv = 0; jv < 7; ++jv) {                       \
        float4 m = *(const float4*)((Bp) + k * D + 4 * jv);                    \
        if (k == 0) {                                                          \
          Cc[4 * jv + 0] = a * m.x;                                            \
          Cc[4 * jv + 1] = a * m.y;                                            \
          Cc[4 * jv + 2] = a * m.z;                                            \
          Cc[4 * jv + 3] = a * m.w;                                            \
        } else {                                                               \
          Cc[4 * jv + 0] = fmaf(a, m.x, Cc[4 * jv + 0]);                       \
          Cc[4 * jv + 1] = fmaf(a, m.y, Cc[4 * jv + 1]);                       \
          Cc[4 * jv + 2] = fmaf(a, m.z, Cc[4 * jv + 2]);                       \
          Cc[4 * jv + 3] = fmaf(a, m.w, Cc[4 * jv + 3]);                       \
        }                                                                      \
      }                                                                        \
    }                                                                          \
  } while (0)

#define LDS_FENCE()                                                            \
  do {                                                                         \
    asm volatile("s_waitcnt lgkmcnt(0)" ::: "memory");                         \
    __builtin_amdgcn_sched_barrier(0);                                         \
  } while (0)

// out[item] = P0 @ P1 @ P2 @ P3 (the 4 phase-1 partials, contiguous per item).
// 2 items per wave: task lanes 0-27 and 32-59; lanes 28-31/60-63 mirror row 27
// (benign duplicates), stores predicated. Single-wave block: no __syncthreads,
// LDS producer->consumer ordered by the wave's own lgkmcnt(0).
__global__ __launch_bounds__(64, 1) void combine4(const float* __restrict__ src,
                                                  float* __restrict__ dst,
                                                  int nitem) {
  __shared__ __align__(16) float Bl[2][2][EMB];  // [buf][tloc][28x28]

  const int lane = threadIdx.x;
  const int tloc = lane >> 5;         // which of the 2 items
  const int rl = lane & 31;           // row within item
  const int rload = rl < D ? rl : D - 1;  // lanes 28-31 mirror row 27
  int item = blockIdx.x * 2 + tloc;
  if (item >= nitem) item = nitem - 1;
  const float* p = src + (size_t)item * 4 * EMB;

  float A0[D], A1[D], B1[D], B2[D], B3[D];

  // Issue ALL global loads upfront (independent -> one latency round-trip).
#pragma unroll
  for (int jv = 0; jv < 7; ++jv) {
    float4 v0 = *(const float4*)(p + rload * D + 4 * jv);
    float4 v1 = *(const float4*)(p + EMB + rload * D + 4 * jv);
    float4 v2 = *(const float4*)(p + 2 * EMB + rload * D + 4 * jv);
    float4 v3 = *(const float4*)(p + 3 * EMB + rload * D + 4 * jv);
    A0[4 * jv + 0] = v0.x; A0[4 * jv + 1] = v0.y;
    A0[4 * jv + 2] = v0.z; A0[4 * jv + 3] = v0.w;
    B1[4 * jv + 0] = v1.x; B1[4 * jv + 1] = v1.y;
    B1[4 * jv + 2] = v1.z; B1[4 * jv + 3] = v1.w;
    B2[4 * jv + 0] = v2.x; B2[4 * jv + 1] = v2.y;
    B2[4 * jv + 2] = v2.z; B2[4 * jv + 3] = v2.w;
    B3[4 * jv + 0] = v3.x; B3[4 * jv + 1] = v3.y;
    B3[4 * jv + 2] = v3.z; B3[4 * jv + 3] = v3.w;
  }

  // Stage P1 -> buf0, P2 -> buf1 (row rload of each; duplicate rows benign).
  {
    float* w0 = &Bl[0][tloc][0] + rload * D;
    float* w1 = &Bl[1][tloc][0] + rload * D;
#pragma unroll
    for (int jv = 0; jv < 7; ++jv) {
      *(float4*)(w0 + 4 * jv) = make_float4(B1[4 * jv + 0], B1[4 * jv + 1],
                                            B1[4 * jv + 2], B1[4 * jv + 3]);
      *(float4*)(w1 + 4 * jv) = make_float4(B2[4 * jv + 0], B2[4 * jv + 1],
                                            B2[4 * jv + 2], B2[4 * jv + 3]);
    }
  }
  LDS_FENCE();

  MATMUL2(A0, A1, &Bl[0][tloc][0]);  // A1 = P0 @ P1
  MATMUL2(A1, A0, &Bl[1][tloc][0]);  // A0 = (P0@P1) @ P2

  // Stage P3 -> buf0 (buf0 reads are earlier in the wave's in-order DS queue).
  {
    float* w0 = &Bl[0][tloc][0] + rload * D;
#pragma unroll
    for (int jv = 0; jv < 7; ++jv)
      *(float4*)(w0 + 4 * jv) = make_float4(B3[4 * jv + 0], B3[4 * jv + 1],
                                            B3[4 * jv + 2], B3[4 * jv + 3]);
  }
  LDS_FENCE();

  MATMUL2(A0, A1, &Bl[0][tloc][0]);  // A1 = (P0@P1@P2) @ P3

  if (rl < D) {
    float* op = dst + (size_t)item * EMB + rl * D;
#pragma unroll
    for (int jv = 0; jv < 7; ++jv)
      *(float4*)(op + 4 * jv) =
          make_float4(A1[4 * jv + 0], A1[4 * jv + 1], A1[4 * jv + 2],
                      A1[4 * jv + 3]);
  }
}

extern "C" void kernel_launch(void* const* d_in, const int* in_sizes, int n_in,
                              void* d_out, int out_size, void* d_ws,
                              size_t ws_size, hipStream_t stream) {
  const float* table = (const float*)d_in[0];
  const int* sent = (const int*)d_in[1];
  float* out = (float*)d_out;

  const size_t need = (size_t)NITEMS * 4 * EMB * sizeof(float);  // 25.7 MB
  if (ws_size >= need) {
    float* pbuf = (float*)d_ws;
    // phase 1: 4 segments of 16 per item -> 8192 partials (contiguous per item)
    const int ntask1 = NITEMS * 4;
    chain_kernel<16, 4, true><<<(ntask1 + IPW - 1) / IPW, 64, 0, stream>>>(
        table, sent, pbuf, ntask1);
    // phase 2: dedicated combiner, 2 items/wave -> grid 1024, fully resident
    combine4<<<(NITEMS + 1) / 2, 64, 0, stream>>>(pbuf, out, NITEMS);
  } else {
    // fallback: direct 64-long chain per item straight into d_out
    chain_kernel<64, 1, true><<<(NITEMS + IPW - 1) / IPW, 64, 0, stream>>>(
        table, sent, out, NITEMS);
  }
}